// Round 1
// baseline (228.621 us; speedup 1.0000x reference)
//
#include <hip/hip_runtime.h>
#include <hip/hip_bf16.h>

// Problem: out[32768,128] = sigmoid(x[32768,1024] @ W[1024,128] + b[128]), all fp32.
// Strategy: bf16 MFMA (16x16x32), W pre-converted+swizzled to B-fragment order in d_ws.

typedef __bf16 bf16x8 __attribute__((ext_vector_type(8)));
typedef float  f32x4  __attribute__((ext_vector_type(4)));

#define DIM   1024
#define NT    128
#define BATCH 32768

// ---------------------------------------------------------------------------
// Prep: W[k][n] fp32 -> bf16 in B-fragment order.
// Layout: wsW[ ((s*8 + c)*64 + lane)*8 + j ] = W[ s*32 + (lane>>4)*8 + j ][ c*16 + (lane&15) ]
//   s = k-step (32 steps of 32), c = col-tile (8 tiles of 16), j = elem in lane's 8.
// Total 1024*128 = 131072 bf16 = 256 KB in d_ws.
// ---------------------------------------------------------------------------
__global__ __launch_bounds__(256) void prep_w(const float* __restrict__ W,
                                              __bf16* __restrict__ wsW) {
    int idx = blockIdx.x * 256 + threadIdx.x;   // 0 .. 131071
    int j = idx & 7;
    int l = (idx >> 3) & 63;
    int c = (idx >> 9) & 7;
    int s = idx >> 12;
    int k = s * 32 + (l >> 4) * 8 + j;
    int n = c * 16 + (l & 15);
    wsW[idx] = (__bf16)W[k * NT + n];
}

// ---------------------------------------------------------------------------
// Main: 256 threads = 4 waves per block. Wave handles 32 rows x 128 cols.
// Block handles 128 rows -> grid = 256 blocks.
// A-frag layout (16x16x32): lane holds A[m = lane&15][k = (lane>>4)*8 + j]
// B-frag layout:            lane holds B[k = (lane>>4)*8 + j][n = lane&15]
// C/D layout:               col = lane&15, row = (lane>>4)*4 + reg
// ---------------------------------------------------------------------------
__global__ __launch_bounds__(256) void gemm_bias_sigmoid(
        const float* __restrict__ x,
        const __bf16* __restrict__ wsW,
        const float* __restrict__ bias,
        float* __restrict__ out) {
    const int lane = threadIdx.x & 63;
    const int wave = threadIdx.x >> 6;
    const int q    = lane >> 4;      // quad
    const int r    = lane & 15;
    const int row0 = blockIdx.x * 128 + wave * 32;

    // Per-lane A base: row (row0 + r), k offset q*8
    const float* xA = x + (size_t)(row0 + r) * DIM + q * 8;
    // B frags: wsW viewed as bf16x8[], index (s*8 + c)*64 + lane
    const bf16x8* wb = (const bf16x8*)wsW + lane;

    f32x4 acc[2][8];
#pragma unroll
    for (int t = 0; t < 2; ++t)
#pragma unroll
        for (int c = 0; c < 8; ++c)
            acc[t][c] = (f32x4){0.f, 0.f, 0.f, 0.f};

    for (int s = 0; s < 32; ++s) {
        // ---- B fragments (L2-resident, fully coalesced 16B/lane) ----
        bf16x8 bfrag[8];
        const bf16x8* wp = wb + (size_t)s * 8 * 64;
#pragma unroll
        for (int c = 0; c < 8; ++c)
            bfrag[c] = wp[(size_t)c * 64];

        // ---- A fragments: 8 contiguous fp32 per lane -> bf16x8 ----
        bf16x8 afrag[2];
#pragma unroll
        for (int t = 0; t < 2; ++t) {
            const float* ap = xA + (size_t)t * 16 * DIM + s * 32;
            float4 a0 = *(const float4*)ap;
            float4 a1 = *(const float4*)(ap + 4);
            bf16x8 af;
            af[0] = (__bf16)a0.x; af[1] = (__bf16)a0.y;
            af[2] = (__bf16)a0.z; af[3] = (__bf16)a0.w;
            af[4] = (__bf16)a1.x; af[5] = (__bf16)a1.y;
            af[6] = (__bf16)a1.z; af[7] = (__bf16)a1.w;
            afrag[t] = af;
        }

        // ---- 16 MFMAs ----
#pragma unroll
        for (int t = 0; t < 2; ++t)
#pragma unroll
            for (int c = 0; c < 8; ++c)
                acc[t][c] = __builtin_amdgcn_mfma_f32_16x16x32_bf16(
                    afrag[t], bfrag[c], acc[t][c], 0, 0, 0);
    }

    // ---- epilogue: bias + sigmoid + store ----
#pragma unroll
    for (int t = 0; t < 2; ++t) {
#pragma unroll
        for (int c = 0; c < 8; ++c) {
            const float bv = bias[c * 16 + r];
#pragma unroll
            for (int reg = 0; reg < 4; ++reg) {
                const int row = row0 + t * 16 + q * 4 + reg;
                float v = acc[t][c][reg] + bv;
                v = 1.0f / (1.0f + __expf(-v));
                out[(size_t)row * NT + c * 16 + r] = v;
            }
        }
    }
}

extern "C" void kernel_launch(void* const* d_in, const int* in_sizes, int n_in,
                              void* d_out, int out_size, void* d_ws, size_t ws_size,
                              hipStream_t stream) {
    const float* x = (const float*)d_in[0];   // [32768,1024]
    const float* W = (const float*)d_in[1];   // [1024,128]
    const float* b = (const float*)d_in[2];   // [128]
    float* out     = (float*)d_out;           // [32768,128]
    __bf16* wsW    = (__bf16*)d_ws;           // 256 KB swizzled bf16 W

    prep_w<<<DIM * NT / 256, 256, 0, stream>>>(W, wsW);
    gemm_bias_sigmoid<<<BATCH / 128, 256, 0, stream>>>(x, wsW, b, out);
}